// Round 16
// baseline (160.646 us; speedup 1.0000x reference)
//
#include <hip/hip_runtime.h>
#include <stdint.h>

// VectorQuantizer — z:(16,256,64,64) f32 -> 65536 rows of 256; emb:(1024,256) f32.
// d_out: q[16777216] | vq_loss[1] | idx_as_float[65536]
//
// R16 = R15 with the K-loop restructured for LDS-read reuse: ks-outer over a
// codetile PAIR, so 4 ds_read_b128 feed 12 MFMAs (3.0 MFMA/read vs R15's 1.5).
// R15 was LDS-co-critical (2.1M b128 reads ~= MFMA cycles). Single-chain accs
// (hh/hl/lh grouped by product, same-acc distance 4 -> no dep stall) keep
// VGPR at ~120 -> 4 waves/SIMD under lb(512,4).

typedef __attribute__((ext_vector_type(8))) short short8;
typedef __attribute__((ext_vector_type(16))) float f32x16;

#define THR_S 1e-3f     // s-space margin threshold (= 2e-3 in dist space)
#define WLCAP 16384

__device__ __forceinline__ unsigned short f2bf(float f) {
    const unsigned int x = __float_as_uint(f);
    return (unsigned short)((x + 0x7FFFu + ((x >> 16) & 1u)) >> 16);
}
__device__ __forceinline__ float bf2f(unsigned short h) {
    return __uint_as_float(((unsigned int)h) << 16);
}

#define MFMA32(A, B, C) __builtin_amdgcn_mfma_f32_32x32x16_bf16(A, B, C, 0, 0, 0)

// ---------------- kernel 0: e prep — transpose-split codebook + norms ----------
__global__ __launch_bounds__(256)
void eprep_kernel(const float* __restrict__ emb, unsigned short* __restrict__ eh_t,
                  unsigned short* __restrict__ el_t, float* __restrict__ enorm,
                  int* __restrict__ wlcnt) {
    const int code = blockIdx.x;
    const int k = threadIdx.x;
    if (code == 0 && k == 0) wlcnt[0] = 0;
    const float v = emb[code * 256 + k];
    const unsigned short h = f2bf(v);
    const int idx = ((k >> 4) << 14) + (code << 4) + (((k >> 3) & 1) << 3) + (k & 7);
    eh_t[idx] = h;
    el_t[idx] = f2bf(v - bf2f(h));
    float s = v * v;
#pragma unroll
    for (int o = 32; o > 0; o >>= 1) s += __shfl_xor(s, o);
    __shared__ float red[4];
    if ((k & 63) == 0) red[k >> 6] = s;
    __syncthreads();
    if (k == 0) enorm[code] = (red[0] + red[1]) + (red[2] + red[3]);
}

// ---------------- kernel 1: MFMA argmin + fused gather/loss ----------------
#define UPD(S, C, B1, I1, B2) { \
    const bool lt_ = (S) < B1; \
    B2 = lt_ ? B1 : fminf(B2, (S)); \
    I1 = lt_ ? (C) : I1; \
    B1 = lt_ ? (S) : B1; }

#define MERGE32(B1, I1, B2) { \
    const float ob1_ = __shfl_xor(B1, 32); \
    const int   oi1_ = __shfl_xor(I1, 32); \
    const float ob2_ = __shfl_xor(B2, 32); \
    const float nb2_ = fminf(fminf(B2, ob2_), fmaxf(B1, ob1_)); \
    if (ob1_ < B1 || (ob1_ == B1 && oi1_ < I1)) { B1 = ob1_; I1 = oi1_; } \
    B2 = nb2_; }

#define PFLD(S, CT, KS) { \
    const int ofs_ = ((KS) << 15) + ((CT) << 10); \
    pf##S##h = *reinterpret_cast<const short8*>(ehp + ofs_); \
    pf##S##l = *reinterpret_cast<const short8*>(elp + ofs_); }

// 4 z-frag reads feed 12 MFMAs; grouped by product so same-acc distance = 4.
#define UNITPAIR(KS, PA, PB) { \
    const int ko_ = (((KS) << 5) + (hi << 4)) ^ rsw; \
    const short8 bh0 = *reinterpret_cast<const short8*>(zbuf + rb0 + ko_); \
    const short8 bl0 = *reinterpret_cast<const short8*>(zbuf + 32768 + rb0 + ko_); \
    const short8 bh1 = *reinterpret_cast<const short8*>(zbuf + rb1 + ko_); \
    const short8 bl1 = *reinterpret_cast<const short8*>(zbuf + 32768 + rb1 + ko_); \
    accA0 = MFMA32(PA##h, bh0, accA0); \
    accA1 = MFMA32(PA##h, bh1, accA1); \
    accB0 = MFMA32(PB##h, bh0, accB0); \
    accB1 = MFMA32(PB##h, bh1, accB1); \
    accA0 = MFMA32(PA##h, bl0, accA0); \
    accA1 = MFMA32(PA##h, bl1, accA1); \
    accB0 = MFMA32(PB##h, bl0, accB0); \
    accB1 = MFMA32(PB##h, bl1, accB1); \
    accA0 = MFMA32(PA##l, bh0, accA0); \
    accA1 = MFMA32(PA##l, bh1, accA1); \
    accB0 = MFMA32(PB##l, bh0, accB0); \
    accB1 = MFMA32(PB##l, bh1, accB1); }

__global__ __launch_bounds__(512, 4)
void argmin_kernel(const float* __restrict__ z, const unsigned short* __restrict__ eh_t,
                   float* __restrict__ idx_out, int* __restrict__ wl,
                   int* __restrict__ wlcnt, const float* __restrict__ emb,
                   float* __restrict__ q_out, float* __restrict__ partials) {
    __shared__ char zbuf[65536];          // zh 32K | zl 32K: byte = row*512 + (2k ^ ((row&7)<<4))
    __shared__ float m_b1[8][64];
    __shared__ int   m_i1[8][64];
    __shared__ float m_b2[8][64];
    __shared__ int   fidx_s[64];

    const int t = threadIdx.x;
    const int l = t & 63;
    const int w = t >> 6;
    const int cl = l & 31;
    const int hi = l >> 5;

    const float* zblk = z + (size_t)blockIdx.x * 16384;

    // ---- stage z: fp32 -> bf16 hi/lo into swizzled LDS (once) ----
#pragma unroll
    for (int i = 0; i < 8; ++i) {
        const int idx = i * 2048 + t * 4;
        const int row = idx >> 8, k = idx & 255;
        const float4 v = *reinterpret_cast<const float4*>(zblk + idx);
        ushort4 hv, lv;
        hv.x = f2bf(v.x); lv.x = f2bf(v.x - bf2f(hv.x));
        hv.y = f2bf(v.y); lv.y = f2bf(v.y - bf2f(hv.y));
        hv.z = f2bf(v.z); lv.z = f2bf(v.z - bf2f(hv.z));
        hv.w = f2bf(v.w); lv.w = f2bf(v.w - bf2f(hv.w));
        const int boff = row * 512 + ((k << 1) ^ ((row & 7) << 4));
        *reinterpret_cast<ushort4*>(zbuf + boff) = hv;
        *reinterpret_cast<ushort4*>(zbuf + 32768 + boff) = lv;
    }
    __syncthreads();

    const char* ehp = (const char*)eh_t + (w * 128 + cl) * 32 + hi * 16;
    const char* elp = ehp + 524288;

    const int rb0 = cl * 512;
    const int rb1 = rb0 + 16384;
    const int rsw = (cl & 7) << 4;

    float b1a = 3.4e38f, b2a = 3.4e38f, b1b = 3.4e38f, b2b = 3.4e38f;
    int   i1a = 0, i1b = 0;

    short8 pf0h, pf0l, pf1h, pf1l, pf2h, pf2l, pf3h, pf3l;

#pragma unroll 1
    for (int cp = 0; cp < 2; ++cp) {
        const int c0 = cp * 2, c1 = cp * 2 + 1;
        f32x16 accA0, accA1, accB0, accB1;   // [ct in pair][rowtile]
#pragma unroll
        for (int j = 0; j < 16; ++j) { accA0[j] = 0.f; accA1[j] = 0.f; accB0[j] = 0.f; accB1[j] = 0.f; }

        PFLD(0, c0, 0) PFLD(1, c1, 0) PFLD(2, c0, 1) PFLD(3, c1, 1)

#pragma unroll 1
        for (int ks = 0; ks < 16; ks += 2) {
            UNITPAIR(ks, pf0, pf1)
            if (ks < 14) { PFLD(0, c0, ks + 2) PFLD(1, c1, ks + 2) }
            UNITPAIR(ks + 1, pf2, pf3)
            if (ks < 13) { PFLD(2, c0, ks + 3) PFLD(3, c1, ks + 3) }
        }

        // ---- pair epilogue: s = -dot, fold into running (b1, i1, b2) ----
        const int codeA = w * 128 + (c0 << 5) + (hi << 2);
        const int codeB = w * 128 + (c1 << 5) + (hi << 2);
#pragma unroll
        for (int reg = 0; reg < 16; ++reg) {
            const int co = (reg & 3) + ((reg >> 2) << 3);
            const int cA = codeA + co, cB = codeB + co;
            UPD(-accA0[reg], cA, b1a, i1a, b2a)
            UPD(-accA1[reg], cA, b1b, i1b, b2b)
            UPD(-accB0[reg], cB, b1a, i1a, b2a)
            UPD(-accB1[reg], cB, b1b, i1b, b2b)
        }
    }

    MERGE32(b1a, i1a, b2a)
    MERGE32(b1b, i1b, b2b)
    if (l < 32) {
        m_b1[w][cl] = b1a;      m_i1[w][cl] = i1a;      m_b2[w][cl] = b2a;
        m_b1[w][cl + 32] = b1b; m_i1[w][cl + 32] = i1b; m_b2[w][cl + 32] = b2b;
    }
    __syncthreads();
    if (t < 64) {
        float b1 = m_b1[0][t]; int i1 = m_i1[0][t]; float b2 = m_b2[0][t];
#pragma unroll
        for (int g = 1; g < 8; ++g) {
            const float ob1 = m_b1[g][t]; const int oi1 = m_i1[g][t]; const float ob2 = m_b2[g][t];
            const float nb2 = fminf(fminf(b2, ob2), fmaxf(b1, ob1));
            if (ob1 < b1 || (ob1 == b1 && oi1 < i1)) { b1 = ob1; i1 = oi1; }
            b2 = nb2;
        }
        const int grow = blockIdx.x * 64 + t;
        idx_out[grow] = (float)i1;
        fidx_s[t] = i1;
        if (b2 - b1 < THR_S) {
            const int pos = atomicAdd(wlcnt, 1);
            if (pos < WLCAP) wl[pos] = grow;
        }
    }

    // ---- fused gather + loss partial (skipped in fallback mode) ----
    if (q_out != nullptr) {
        __syncthreads();   // fidx_s visible
        float lsum = 0.f;
        float* qblk = q_out + (size_t)blockIdx.x * 16384;
#pragma unroll
        for (int i = 0; i < 8; ++i) {
            const int row = i * 8 + w;     // wave w handles row i*8+w (uniform)
            const int code = fidx_s[row];
            const float4 e4 = *reinterpret_cast<const float4*>(
                emb + (size_t)code * 256 + l * 4);
            const int byt = row * 512 + ((l * 8) ^ ((row & 7) << 4));
            const ushort4 h4 = *reinterpret_cast<const ushort4*>(zbuf + byt);
            const ushort4 l4 = *reinterpret_cast<const ushort4*>(zbuf + 32768 + byt);
            const float zx = bf2f(h4.x) + bf2f(l4.x);
            const float zy = bf2f(h4.y) + bf2f(l4.y);
            const float zz = bf2f(h4.z) + bf2f(l4.z);
            const float zw = bf2f(h4.w) + bf2f(l4.w);
            const float dx = e4.x - zx, dy = e4.y - zy, dz = e4.z - zz, dw = e4.w - zw;
            lsum += dx * dx + dy * dy + dz * dz + dw * dw;
            *reinterpret_cast<float4*>(qblk + row * 256 + l * 4) = e4;
        }
#pragma unroll
        for (int o = 32; o > 0; o >>= 1) lsum += __shfl_xor(lsum, o);
        if (l == 0) m_b1[0][w] = lsum;    // reuse merge LDS as scratch
        __syncthreads();
        if (t == 0) {
            float s = 0.f;
#pragma unroll
            for (int g = 0; g < 8; ++g) s += m_b1[0][g];
            partials[blockIdx.x] = s;
        }
    }
}

// ---------------- kernel 2: exact fp32 fixup (+ q patch, loss delta) ----------
__global__ __launch_bounds__(256)
void fixup_kernel(const float* __restrict__ z, const float* __restrict__ emb,
                  const float* __restrict__ enorm_g, const int* __restrict__ wl,
                  const int* __restrict__ wlcnt, float* __restrict__ idx_out,
                  float* __restrict__ q_out, float* __restrict__ wl_delta) {
    __shared__ float zrow[256];
    __shared__ float znred[4];
    __shared__ float mb[4];
    __shared__ int   mi[4];
    __shared__ int   fin_s;
    __shared__ float dred[4];

    const int t = threadIdx.x;
    const int l = t & 63, wv = t >> 6;
    const int dq = l & 3, tx = (l >> 2) & 15;

    int n = wlcnt[0];
    if (n > WLCAP) n = WLCAP;

#pragma unroll 1
    for (int i = blockIdx.x; i < n; i += 256) {
        const int r = wl[i];
        const float v = z[(size_t)r * 256 + t];
        zrow[t] = v;
        float zn = v * v;
#pragma unroll
        for (int o = 32; o > 0; o >>= 1) zn += __shfl_xor(zn, o);
        if (l == 0) znred[wv] = zn;
        __syncthreads();
        const float znf = (znred[0] + znred[1]) + (znred[2] + znred[3]);

        float b1 = 3.4e38f;
        int   i1 = 0;
#pragma unroll 1
        for (int cc = 0; cc < 16; ++cc) {
            const int c = wv * 256 + cc * 16 + tx;
            const float* er = emb + (size_t)c * 256 + dq * 4;
            float dot = 0.f;
#pragma unroll
            for (int j = 0; j < 16; ++j) {
                const float4 ev = *reinterpret_cast<const float4*>(er + j * 16);
                const float4 zv = *reinterpret_cast<const float4*>(&zrow[j * 16 + dq * 4]);
                dot = fmaf(zv.x, ev.x, dot);
                dot = fmaf(zv.y, ev.y, dot);
                dot = fmaf(zv.z, ev.z, dot);
                dot = fmaf(zv.w, ev.w, dot);
            }
            dot += __shfl_xor(dot, 1);
            dot += __shfl_xor(dot, 2);
            const float dist = fmaf(-2.f, dot, znf + enorm_g[c]);
            if (dist < b1) { b1 = dist; i1 = c; }
        }
#pragma unroll
        for (int off = 4; off < 64; off <<= 1) {
            const float ov = __shfl_xor(b1, off);
            const int   oi = __shfl_xor(i1, off);
            if (ov < b1 || (ov == b1 && oi < i1)) { b1 = ov; i1 = oi; }
        }
        if (l == 0) { mb[wv] = b1; mi[wv] = i1; }
        __syncthreads();
        if (t == 0) {
            float fb = mb[0]; int fi = mi[0];
#pragma unroll
            for (int g = 1; g < 4; ++g)
                if (mb[g] < fb || (mb[g] == fb && mi[g] < fi)) { fb = mb[g]; fi = mi[g]; }
            fin_s = fi;
        }
        __syncthreads();
        const int fi = fin_s;
        if (wl_delta != nullptr) {
            const int oldi = (int)idx_out[r];
            float d = 0.f;
            if (fi != oldi) {
                const float en_ = emb[(size_t)fi * 256 + t];
                const float eo_ = emb[(size_t)oldi * 256 + t];
                const float zt = zrow[t];
                d = (en_ - zt) * (en_ - zt) - (eo_ - zt) * (eo_ - zt);
                q_out[(size_t)r * 256 + t] = en_;
            }
#pragma unroll
            for (int o = 32; o > 0; o >>= 1) d += __shfl_xor(d, o);
            if (l == 0) dred[wv] = d;
            __syncthreads();
            if (t == 0) {
                wl_delta[i] = (dred[0] + dred[1]) + (dred[2] + dred[3]);
                idx_out[r] = (float)fi;
            }
        } else {
            if (t == 0) idx_out[r] = (float)fi;
        }
        __syncthreads();   // LDS reused next iteration
    }
}

// ---------------- kernel 3 (fused path): loss = partials + deltas -------------
__global__ __launch_bounds__(256)
void loss_kernel(const float* __restrict__ partials, const float* __restrict__ wl_delta,
                 const int* __restrict__ wlcnt, float* __restrict__ loss_out) {
    const int tid = threadIdx.x;
    float s = partials[tid] + partials[tid + 256] + partials[tid + 512] + partials[tid + 768];
    int n = wlcnt[0];
    if (n > WLCAP) n = WLCAP;
    for (int i = tid; i < n; i += 256) s += wl_delta[i];
#pragma unroll
    for (int off = 32; off > 0; off >>= 1) s += __shfl_xor(s, off);
    __shared__ float red[4];
    if ((tid & 63) == 0) red[tid >> 6] = s;
    __syncthreads();
    if (tid == 0)
        loss_out[0] = ((red[0] + red[1]) + (red[2] + red[3])) * (1.25f / 16777216.0f);
}

// ---------------- fallback kernels (R13 flow, if ws too small) ----------------
__global__ __launch_bounds__(256)
void gather_kernel(const float* __restrict__ z, const float* __restrict__ emb,
                   const float* __restrict__ idx_f, float* __restrict__ q_out,
                   float* __restrict__ partials) {
    const int wv = threadIdx.x >> 6, ln = threadIdx.x & 63;
    float lsum = 0.f;
#pragma unroll
    for (int i = 0; i < 8; ++i) {
        const size_t row = (size_t)blockIdx.x * 32 + i * 4 + wv;
        const int kidx = (int)idx_f[row];
        const float4 e4 = *reinterpret_cast<const float4*>(emb + (size_t)kidx * 256 + ln * 4);
        const float4 z4 = *reinterpret_cast<const float4*>(z + row * 256 + ln * 4);
        *reinterpret_cast<float4*>(q_out + row * 256 + ln * 4) = e4;
        const float dx = e4.x - z4.x, dy = e4.y - z4.y, dz = e4.z - z4.z, dw = e4.w - z4.w;
        lsum += dx * dx + dy * dy + dz * dz + dw * dw;
    }
#pragma unroll
    for (int off = 32; off > 0; off >>= 1) lsum += __shfl_xor(lsum, off);
    __shared__ float red[4];
    if (ln == 0) red[wv] = lsum;
    __syncthreads();
    if (threadIdx.x == 0) partials[blockIdx.x] = red[0] + red[1] + red[2] + red[3];
}

__global__ __launch_bounds__(256)
void loss_fb_kernel(const float* __restrict__ partials, float* __restrict__ loss_out) {
    const int tid = threadIdx.x;
    float s = 0.f;
#pragma unroll
    for (int i = 0; i < 8; ++i) s += partials[tid + i * 256];
#pragma unroll
    for (int off = 32; off > 0; off >>= 1) s += __shfl_xor(s, off);
    __shared__ float red[4];
    if ((tid & 63) == 0) red[tid >> 6] = s;
    __syncthreads();
    if (tid == 0)
        loss_out[0] = (red[0] + red[1] + red[2] + red[3]) * (1.25f / 16777216.0f);
}

extern "C" void kernel_launch(void* const* d_in, const int* in_sizes, int n_in,
                              void* d_out, int out_size, void* d_ws, size_t ws_size,
                              hipStream_t stream) {
    const float* z   = (const float*)d_in[0];
    const float* emb = (const float*)d_in[1];
    float* out      = (float*)d_out;
    float* q_out    = out;                       // 16,777,216 floats
    float* loss_out = out + 16777216;            // 1 float
    float* idx_out  = out + 16777217;            // 65,536 floats

    // ws layout (floats): eh_t[131072] | el_t[131072] | enorm[1024] | partials[2048]
    //                     | wlcnt[64-pad] | wl[16384] | wl_delta[16384]
    const size_t WS_NEEDED = (size_t)298048 * 4;
    float* ws = (float*)d_ws;

    if (ws_size >= WS_NEEDED) {
        unsigned short* eh_t = (unsigned short*)ws;
        unsigned short* el_t = eh_t + 262144;
        float* enorm    = ws + 262144;
        float* partials = ws + 263168;
        int*   wlcnt    = (int*)(ws + 265216);
        int*   wl       = (int*)(ws + 265280);
        float* wl_delta = ws + 281664;

        eprep_kernel<<<1024, 256, 0, stream>>>(emb, eh_t, el_t, enorm, wlcnt);
        argmin_kernel<<<1024, 512, 0, stream>>>(z, eh_t, idx_out, wl, wlcnt,
                                                emb, q_out, partials);
        fixup_kernel<<<256, 256, 0, stream>>>(z, emb, enorm, wl, wlcnt, idx_out,
                                              q_out, wl_delta);
        loss_kernel<<<1, 256, 0, stream>>>(partials, wl_delta, wlcnt, loss_out);
    } else {
        // fallback: R13 flow, codebook scratch inside q (rewritten by gather)
        unsigned short* eh_t = (unsigned short*)q_out;
        unsigned short* el_t = eh_t + 262144;
        int*   wl    = (int*)(q_out + 262144);
        int*   wlcnt = (int*)(q_out + 327680);
        float* enorm    = ws;            // 1024
        float* partials = ws + 1024;     // 2048

        eprep_kernel<<<1024, 256, 0, stream>>>(emb, eh_t, el_t, enorm, wlcnt);
        argmin_kernel<<<1024, 512, 0, stream>>>(z, eh_t, idx_out, wl, wlcnt,
                                                emb, nullptr, nullptr);
        fixup_kernel<<<256, 256, 0, stream>>>(z, emb, enorm, wl, wlcnt, idx_out,
                                              nullptr, nullptr);
        gather_kernel<<<2048, 256, 0, stream>>>(z, emb, idx_out, q_out, partials);
        loss_fb_kernel<<<1, 256, 0, stream>>>(partials, loss_out);
    }
}

// Round 17
// 156.842 us; speedup vs baseline: 1.0243x; 1.0243x over previous
//
#include <hip/hip_runtime.h>
#include <stdint.h>

// VectorQuantizer — z:(16,256,64,64) f32 -> 65536 rows of 256; emb:(1024,256) f32.
// d_out: q[16777216] | vq_loss[1] | idx_as_float[65536]
//
// R17 = R16 (ks-outer codetile-pair loop, 3.0 MFMA per ds_read) with B-fragment
// liveness halved: UNITPAIR split into two rowtile halves (8 b-frag VGPRs live
// instead of 16). R16 spilled ~27MB (WRITE 94.5MB vs 68MB q) because acc 64 +
// pf 32 + bfrag 16 + misc > lb(512,4)'s 128 cap. Per-acc MFMA order unchanged.

typedef __attribute__((ext_vector_type(8))) short short8;
typedef __attribute__((ext_vector_type(16))) float f32x16;

#define THR_S 1e-3f     // s-space margin threshold (= 2e-3 in dist space)
#define WLCAP 16384

__device__ __forceinline__ unsigned short f2bf(float f) {
    const unsigned int x = __float_as_uint(f);
    return (unsigned short)((x + 0x7FFFu + ((x >> 16) & 1u)) >> 16);
}
__device__ __forceinline__ float bf2f(unsigned short h) {
    return __uint_as_float(((unsigned int)h) << 16);
}

#define MFMA32(A, B, C) __builtin_amdgcn_mfma_f32_32x32x16_bf16(A, B, C, 0, 0, 0)

// ---------------- kernel 0: e prep — transpose-split codebook + norms ----------
__global__ __launch_bounds__(256)
void eprep_kernel(const float* __restrict__ emb, unsigned short* __restrict__ eh_t,
                  unsigned short* __restrict__ el_t, float* __restrict__ enorm,
                  int* __restrict__ wlcnt) {
    const int code = blockIdx.x;
    const int k = threadIdx.x;
    if (code == 0 && k == 0) wlcnt[0] = 0;
    const float v = emb[code * 256 + k];
    const unsigned short h = f2bf(v);
    const int idx = ((k >> 4) << 14) + (code << 4) + (((k >> 3) & 1) << 3) + (k & 7);
    eh_t[idx] = h;
    el_t[idx] = f2bf(v - bf2f(h));
    float s = v * v;
#pragma unroll
    for (int o = 32; o > 0; o >>= 1) s += __shfl_xor(s, o);
    __shared__ float red[4];
    if ((k & 63) == 0) red[k >> 6] = s;
    __syncthreads();
    if (k == 0) enorm[code] = (red[0] + red[1]) + (red[2] + red[3]);
}

// ---------------- kernel 1: MFMA argmin + fused gather/loss ----------------
#define UPD(S, C, B1, I1, B2) { \
    const bool lt_ = (S) < B1; \
    B2 = lt_ ? B1 : fminf(B2, (S)); \
    I1 = lt_ ? (C) : I1; \
    B1 = lt_ ? (S) : B1; }

#define MERGE32(B1, I1, B2) { \
    const float ob1_ = __shfl_xor(B1, 32); \
    const int   oi1_ = __shfl_xor(I1, 32); \
    const float ob2_ = __shfl_xor(B2, 32); \
    const float nb2_ = fminf(fminf(B2, ob2_), fmaxf(B1, ob1_)); \
    if (ob1_ < B1 || (ob1_ == B1 && oi1_ < I1)) { B1 = ob1_; I1 = oi1_; } \
    B2 = nb2_; }

#define PFLD(S, CT, KS) { \
    const int ofs_ = ((KS) << 15) + ((CT) << 10); \
    pf##S##h = *reinterpret_cast<const short8*>(ehp + ofs_); \
    pf##S##l = *reinterpret_cast<const short8*>(elp + ofs_); }

// 4 z-frag reads feed 12 MFMAs, split by rowtile so only 8 b-frag VGPRs live.
// Per-acc product order: hh, hl, lh (same as R15/R16 -> same numerics).
#define UNITPAIR(KS, PA, PB) { \
    const int ko_ = (((KS) << 5) + (hi << 4)) ^ rsw; \
    { \
        const short8 bh0 = *reinterpret_cast<const short8*>(zbuf + rb0 + ko_); \
        const short8 bl0 = *reinterpret_cast<const short8*>(zbuf + 32768 + rb0 + ko_); \
        accA0 = MFMA32(PA##h, bh0, accA0); \
        accB0 = MFMA32(PB##h, bh0, accB0); \
        accA0 = MFMA32(PA##h, bl0, accA0); \
        accB0 = MFMA32(PB##h, bl0, accB0); \
        accA0 = MFMA32(PA##l, bh0, accA0); \
        accB0 = MFMA32(PB##l, bh0, accB0); \
    } \
    { \
        const short8 bh1 = *reinterpret_cast<const short8*>(zbuf + rb1 + ko_); \
        const short8 bl1 = *reinterpret_cast<const short8*>(zbuf + 32768 + rb1 + ko_); \
        accA1 = MFMA32(PA##h, bh1, accA1); \
        accB1 = MFMA32(PB##h, bh1, accB1); \
        accA1 = MFMA32(PA##h, bl1, accA1); \
        accB1 = MFMA32(PB##h, bl1, accB1); \
        accA1 = MFMA32(PA##l, bh1, accA1); \
        accB1 = MFMA32(PB##l, bh1, accB1); \
    } }

__global__ __launch_bounds__(512, 4)
void argmin_kernel(const float* __restrict__ z, const unsigned short* __restrict__ eh_t,
                   float* __restrict__ idx_out, int* __restrict__ wl,
                   int* __restrict__ wlcnt, const float* __restrict__ emb,
                   float* __restrict__ q_out, float* __restrict__ partials) {
    __shared__ char zbuf[65536];          // zh 32K | zl 32K: byte = row*512 + (2k ^ ((row&7)<<4))
    __shared__ float m_b1[8][64];
    __shared__ int   m_i1[8][64];
    __shared__ float m_b2[8][64];
    __shared__ int   fidx_s[64];

    const int t = threadIdx.x;
    const int l = t & 63;
    const int w = t >> 6;
    const int cl = l & 31;
    const int hi = l >> 5;

    const float* zblk = z + (size_t)blockIdx.x * 16384;

    // ---- stage z: fp32 -> bf16 hi/lo into swizzled LDS (once) ----
#pragma unroll
    for (int i = 0; i < 8; ++i) {
        const int idx = i * 2048 + t * 4;
        const int row = idx >> 8, k = idx & 255;
        const float4 v = *reinterpret_cast<const float4*>(zblk + idx);
        ushort4 hv, lv;
        hv.x = f2bf(v.x); lv.x = f2bf(v.x - bf2f(hv.x));
        hv.y = f2bf(v.y); lv.y = f2bf(v.y - bf2f(hv.y));
        hv.z = f2bf(v.z); lv.z = f2bf(v.z - bf2f(hv.z));
        hv.w = f2bf(v.w); lv.w = f2bf(v.w - bf2f(hv.w));
        const int boff = row * 512 + ((k << 1) ^ ((row & 7) << 4));
        *reinterpret_cast<ushort4*>(zbuf + boff) = hv;
        *reinterpret_cast<ushort4*>(zbuf + 32768 + boff) = lv;
    }
    __syncthreads();

    const char* ehp = (const char*)eh_t + (w * 128 + cl) * 32 + hi * 16;
    const char* elp = ehp + 524288;

    const int rb0 = cl * 512;
    const int rb1 = rb0 + 16384;
    const int rsw = (cl & 7) << 4;

    float b1a = 3.4e38f, b2a = 3.4e38f, b1b = 3.4e38f, b2b = 3.4e38f;
    int   i1a = 0, i1b = 0;

    short8 pf0h, pf0l, pf1h, pf1l, pf2h, pf2l, pf3h, pf3l;

#pragma unroll 1
    for (int cp = 0; cp < 2; ++cp) {
        const int c0 = cp * 2, c1 = cp * 2 + 1;
        f32x16 accA0, accA1, accB0, accB1;   // [ct in pair][rowtile]
#pragma unroll
        for (int j = 0; j < 16; ++j) { accA0[j] = 0.f; accA1[j] = 0.f; accB0[j] = 0.f; accB1[j] = 0.f; }

        PFLD(0, c0, 0) PFLD(1, c1, 0) PFLD(2, c0, 1) PFLD(3, c1, 1)

#pragma unroll 1
        for (int ks = 0; ks < 16; ks += 2) {
            UNITPAIR(ks, pf0, pf1)
            if (ks < 14) { PFLD(0, c0, ks + 2) PFLD(1, c1, ks + 2) }
            UNITPAIR(ks + 1, pf2, pf3)
            if (ks < 13) { PFLD(2, c0, ks + 3) PFLD(3, c1, ks + 3) }
        }

        // ---- pair epilogue: s = -dot, fold into running (b1, i1, b2) ----
        const int codeA = w * 128 + (c0 << 5) + (hi << 2);
        const int codeB = w * 128 + (c1 << 5) + (hi << 2);
#pragma unroll
        for (int reg = 0; reg < 16; ++reg) {
            const int co = (reg & 3) + ((reg >> 2) << 3);
            const int cA = codeA + co, cB = codeB + co;
            UPD(-accA0[reg], cA, b1a, i1a, b2a)
            UPD(-accA1[reg], cA, b1b, i1b, b2b)
            UPD(-accB0[reg], cB, b1a, i1a, b2a)
            UPD(-accB1[reg], cB, b1b, i1b, b2b)
        }
    }

    MERGE32(b1a, i1a, b2a)
    MERGE32(b1b, i1b, b2b)
    if (l < 32) {
        m_b1[w][cl] = b1a;      m_i1[w][cl] = i1a;      m_b2[w][cl] = b2a;
        m_b1[w][cl + 32] = b1b; m_i1[w][cl + 32] = i1b; m_b2[w][cl + 32] = b2b;
    }
    __syncthreads();
    if (t < 64) {
        float b1 = m_b1[0][t]; int i1 = m_i1[0][t]; float b2 = m_b2[0][t];
#pragma unroll
        for (int g = 1; g < 8; ++g) {
            const float ob1 = m_b1[g][t]; const int oi1 = m_i1[g][t]; const float ob2 = m_b2[g][t];
            const float nb2 = fminf(fminf(b2, ob2), fmaxf(b1, ob1));
            if (ob1 < b1 || (ob1 == b1 && oi1 < i1)) { b1 = ob1; i1 = oi1; }
            b2 = nb2;
        }
        const int grow = blockIdx.x * 64 + t;
        idx_out[grow] = (float)i1;
        fidx_s[t] = i1;
        if (b2 - b1 < THR_S) {
            const int pos = atomicAdd(wlcnt, 1);
            if (pos < WLCAP) wl[pos] = grow;
        }
    }

    // ---- fused gather + loss partial (skipped in fallback mode) ----
    if (q_out != nullptr) {
        __syncthreads();   // fidx_s visible
        float lsum = 0.f;
        float* qblk = q_out + (size_t)blockIdx.x * 16384;
#pragma unroll
        for (int i = 0; i < 8; ++i) {
            const int row = i * 8 + w;     // wave w handles row i*8+w (uniform)
            const int code = fidx_s[row];
            const float4 e4 = *reinterpret_cast<const float4*>(
                emb + (size_t)code * 256 + l * 4);
            const int byt = row * 512 + ((l * 8) ^ ((row & 7) << 4));
            const ushort4 h4 = *reinterpret_cast<const ushort4*>(zbuf + byt);
            const ushort4 l4 = *reinterpret_cast<const ushort4*>(zbuf + 32768 + byt);
            const float zx = bf2f(h4.x) + bf2f(l4.x);
            const float zy = bf2f(h4.y) + bf2f(l4.y);
            const float zz = bf2f(h4.z) + bf2f(l4.z);
            const float zw = bf2f(h4.w) + bf2f(l4.w);
            const float dx = e4.x - zx, dy = e4.y - zy, dz = e4.z - zz, dw = e4.w - zw;
            lsum += dx * dx + dy * dy + dz * dz + dw * dw;
            *reinterpret_cast<float4*>(qblk + row * 256 + l * 4) = e4;
        }
#pragma unroll
        for (int o = 32; o > 0; o >>= 1) lsum += __shfl_xor(lsum, o);
        if (l == 0) m_b1[0][w] = lsum;    // reuse merge LDS as scratch
        __syncthreads();
        if (t == 0) {
            float s = 0.f;
#pragma unroll
            for (int g = 0; g < 8; ++g) s += m_b1[0][g];
            partials[blockIdx.x] = s;
        }
    }
}

// ---------------- kernel 2: exact fp32 fixup (+ q patch, loss delta) ----------
__global__ __launch_bounds__(256)
void fixup_kernel(const float* __restrict__ z, const float* __restrict__ emb,
                  const float* __restrict__ enorm_g, const int* __restrict__ wl,
                  const int* __restrict__ wlcnt, float* __restrict__ idx_out,
                  float* __restrict__ q_out, float* __restrict__ wl_delta) {
    __shared__ float zrow[256];
    __shared__ float znred[4];
    __shared__ float mb[4];
    __shared__ int   mi[4];
    __shared__ int   fin_s;
    __shared__ float dred[4];

    const int t = threadIdx.x;
    const int l = t & 63, wv = t >> 6;
    const int dq = l & 3, tx = (l >> 2) & 15;

    int n = wlcnt[0];
    if (n > WLCAP) n = WLCAP;

#pragma unroll 1
    for (int i = blockIdx.x; i < n; i += 256) {
        const int r = wl[i];
        const float v = z[(size_t)r * 256 + t];
        zrow[t] = v;
        float zn = v * v;
#pragma unroll
        for (int o = 32; o > 0; o >>= 1) zn += __shfl_xor(zn, o);
        if (l == 0) znred[wv] = zn;
        __syncthreads();
        const float znf = (znred[0] + znred[1]) + (znred[2] + znred[3]);

        float b1 = 3.4e38f;
        int   i1 = 0;
#pragma unroll 1
        for (int cc = 0; cc < 16; ++cc) {
            const int c = wv * 256 + cc * 16 + tx;
            const float* er = emb + (size_t)c * 256 + dq * 4;
            float dot = 0.f;
#pragma unroll
            for (int j = 0; j < 16; ++j) {
                const float4 ev = *reinterpret_cast<const float4*>(er + j * 16);
                const float4 zv = *reinterpret_cast<const float4*>(&zrow[j * 16 + dq * 4]);
                dot = fmaf(zv.x, ev.x, dot);
                dot = fmaf(zv.y, ev.y, dot);
                dot = fmaf(zv.z, ev.z, dot);
                dot = fmaf(zv.w, ev.w, dot);
            }
            dot += __shfl_xor(dot, 1);
            dot += __shfl_xor(dot, 2);
            const float dist = fmaf(-2.f, dot, znf + enorm_g[c]);
            if (dist < b1) { b1 = dist; i1 = c; }
        }
#pragma unroll
        for (int off = 4; off < 64; off <<= 1) {
            const float ov = __shfl_xor(b1, off);
            const int   oi = __shfl_xor(i1, off);
            if (ov < b1 || (ov == b1 && oi < i1)) { b1 = ov; i1 = oi; }
        }
        if (l == 0) { mb[wv] = b1; mi[wv] = i1; }
        __syncthreads();
        if (t == 0) {
            float fb = mb[0]; int fi = mi[0];
#pragma unroll
            for (int g = 1; g < 4; ++g)
                if (mb[g] < fb || (mb[g] == fb && mi[g] < fi)) { fb = mb[g]; fi = mi[g]; }
            fin_s = fi;
        }
        __syncthreads();
        const int fi = fin_s;
        if (wl_delta != nullptr) {
            const int oldi = (int)idx_out[r];
            float d = 0.f;
            if (fi != oldi) {
                const float en_ = emb[(size_t)fi * 256 + t];
                const float eo_ = emb[(size_t)oldi * 256 + t];
                const float zt = zrow[t];
                d = (en_ - zt) * (en_ - zt) - (eo_ - zt) * (eo_ - zt);
                q_out[(size_t)r * 256 + t] = en_;
            }
#pragma unroll
            for (int o = 32; o > 0; o >>= 1) d += __shfl_xor(d, o);
            if (l == 0) dred[wv] = d;
            __syncthreads();
            if (t == 0) {
                wl_delta[i] = (dred[0] + dred[1]) + (dred[2] + dred[3]);
                idx_out[r] = (float)fi;
            }
        } else {
            if (t == 0) idx_out[r] = (float)fi;
        }
        __syncthreads();   // LDS reused next iteration
    }
}

// ---------------- kernel 3 (fused path): loss = partials + deltas -------------
__global__ __launch_bounds__(256)
void loss_kernel(const float* __restrict__ partials, const float* __restrict__ wl_delta,
                 const int* __restrict__ wlcnt, float* __restrict__ loss_out) {
    const int tid = threadIdx.x;
    float s = partials[tid] + partials[tid + 256] + partials[tid + 512] + partials[tid + 768];
    int n = wlcnt[0];
    if (n > WLCAP) n = WLCAP;
    for (int i = tid; i < n; i += 256) s += wl_delta[i];
#pragma unroll
    for (int off = 32; off > 0; off >>= 1) s += __shfl_xor(s, off);
    __shared__ float red[4];
    if ((tid & 63) == 0) red[tid >> 6] = s;
    __syncthreads();
    if (tid == 0)
        loss_out[0] = ((red[0] + red[1]) + (red[2] + red[3])) * (1.25f / 16777216.0f);
}

// ---------------- fallback kernels (R13 flow, if ws too small) ----------------
__global__ __launch_bounds__(256)
void gather_kernel(const float* __restrict__ z, const float* __restrict__ emb,
                   const float* __restrict__ idx_f, float* __restrict__ q_out,
                   float* __restrict__ partials) {
    const int wv = threadIdx.x >> 6, ln = threadIdx.x & 63;
    float lsum = 0.f;
#pragma unroll
    for (int i = 0; i < 8; ++i) {
        const size_t row = (size_t)blockIdx.x * 32 + i * 4 + wv;
        const int kidx = (int)idx_f[row];
        const float4 e4 = *reinterpret_cast<const float4*>(emb + (size_t)kidx * 256 + ln * 4);
        const float4 z4 = *reinterpret_cast<const float4*>(z + row * 256 + ln * 4);
        *reinterpret_cast<float4*>(q_out + row * 256 + ln * 4) = e4;
        const float dx = e4.x - z4.x, dy = e4.y - z4.y, dz = e4.z - z4.z, dw = e4.w - z4.w;
        lsum += dx * dx + dy * dy + dz * dz + dw * dw;
    }
#pragma unroll
    for (int off = 32; off > 0; off >>= 1) lsum += __shfl_xor(lsum, off);
    __shared__ float red[4];
    if (ln == 0) red[wv] = lsum;
    __syncthreads();
    if (threadIdx.x == 0) partials[blockIdx.x] = red[0] + red[1] + red[2] + red[3];
}

__global__ __launch_bounds__(256)
void loss_fb_kernel(const float* __restrict__ partials, float* __restrict__ loss_out) {
    const int tid = threadIdx.x;
    float s = 0.f;
#pragma unroll
    for (int i = 0; i < 8; ++i) s += partials[tid + i * 256];
#pragma unroll
    for (int off = 32; off > 0; off >>= 1) s += __shfl_xor(s, off);
    __shared__ float red[4];
    if ((tid & 63) == 0) red[tid >> 6] = s;
    __syncthreads();
    if (tid == 0)
        loss_out[0] = (red[0] + red[1] + red[2] + red[3]) * (1.25f / 16777216.0f);
}

extern "C" void kernel_launch(void* const* d_in, const int* in_sizes, int n_in,
                              void* d_out, int out_size, void* d_ws, size_t ws_size,
                              hipStream_t stream) {
    const float* z   = (const float*)d_in[0];
    const float* emb = (const float*)d_in[1];
    float* out      = (float*)d_out;
    float* q_out    = out;                       // 16,777,216 floats
    float* loss_out = out + 16777216;            // 1 float
    float* idx_out  = out + 16777217;            // 65,536 floats

    // ws layout (floats): eh_t[131072] | el_t[131072] | enorm[1024] | partials[2048]
    //                     | wlcnt[64-pad] | wl[16384] | wl_delta[16384]
    const size_t WS_NEEDED = (size_t)298048 * 4;
    float* ws = (float*)d_ws;

    if (ws_size >= WS_NEEDED) {
        unsigned short* eh_t = (unsigned short*)ws;
        unsigned short* el_t = eh_t + 262144;
        float* enorm    = ws + 262144;
        float* partials = ws + 263168;
        int*   wlcnt    = (int*)(ws + 265216);
        int*   wl       = (int*)(ws + 265280);
        float* wl_delta = ws + 281664;

        eprep_kernel<<<1024, 256, 0, stream>>>(emb, eh_t, el_t, enorm, wlcnt);
        argmin_kernel<<<1024, 512, 0, stream>>>(z, eh_t, idx_out, wl, wlcnt,
                                                emb, q_out, partials);
        fixup_kernel<<<256, 256, 0, stream>>>(z, emb, enorm, wl, wlcnt, idx_out,
                                              q_out, wl_delta);
        loss_kernel<<<1, 256, 0, stream>>>(partials, wl_delta, wlcnt, loss_out);
    } else {
        // fallback: R13 flow, codebook scratch inside q (rewritten by gather)
        unsigned short* eh_t = (unsigned short*)q_out;
        unsigned short* el_t = eh_t + 262144;
        int*   wl    = (int*)(q_out + 262144);
        int*   wlcnt = (int*)(q_out + 327680);
        float* enorm    = ws;            // 1024
        float* partials = ws + 1024;     // 2048

        eprep_kernel<<<1024, 256, 0, stream>>>(emb, eh_t, el_t, enorm, wlcnt);
        argmin_kernel<<<1024, 512, 0, stream>>>(z, eh_t, idx_out, wl, wlcnt,
                                                emb, nullptr, nullptr);
        fixup_kernel<<<256, 256, 0, stream>>>(z, emb, enorm, wl, wlcnt, idx_out,
                                              nullptr, nullptr);
        gather_kernel<<<2048, 256, 0, stream>>>(z, emb, idx_out, q_out, partials);
        loss_fb_kernel<<<1, 256, 0, stream>>>(partials, loss_out);
    }
}